// Round 4
// baseline (488.505 us; speedup 1.0000x reference)
//
#include <hip/hip_runtime.h>

#define BB 16
#define QQ 900
#define CC 92
#define TT 100
#define INFF 1e18f
#define NK 15   // ceil(QQ / 64)

// ---------------- cost kernel: one block per (b,q) ----------------
__global__ __launch_bounds__(128) void cost_kernel(
    const float* __restrict__ logits,   // [B][Q][C]
    const float* __restrict__ pboxes,   // [B][Q][4]
    const int*   __restrict__ tlabels,  // [B][T]
    const float* __restrict__ tboxes,   // [B][T][4]
    float* __restrict__ cost,           // [B][Q][T]
    float* __restrict__ costT)          // [B][T][Q] or nullptr
{
  const int bq  = blockIdx.x;          // b*QQ + q
  const int b   = bq / QQ;
  const int q   = bq - b * QQ;
  const int tid = threadIdx.x;

  __shared__ float sl[CC];
  __shared__ float red[128];
  __shared__ float s_max, s_sum;

  float lv = (tid < CC) ? logits[(size_t)bq * CC + tid] : -3.402823466e38f;
  if (tid < CC) sl[tid] = lv;
  red[tid] = lv;
  __syncthreads();
  for (int s = 64; s > 0; s >>= 1) {
    if (tid < s) red[tid] = fmaxf(red[tid], red[tid + s]);
    __syncthreads();
  }
  if (tid == 0) s_max = red[0];
  __syncthreads();

  float e = (tid < CC) ? expf(lv - s_max) : 0.0f;
  if (tid < CC) sl[tid] = e;           // sl now holds exp(l - max)
  red[tid] = e;
  __syncthreads();
  for (int s = 64; s > 0; s >>= 1) {
    if (tid < s) red[tid] += red[tid + s];
    __syncthreads();
  }
  if (tid == 0) s_sum = red[0];
  __syncthreads();

  const float4 pbv = ((const float4*)pboxes)[bq];
  const float pax1 = pbv.x - 0.5f * pbv.z, pay1 = pbv.y - 0.5f * pbv.w;
  const float pax2 = pbv.x + 0.5f * pbv.z, pay2 = pbv.y + 0.5f * pbv.w;
  const float area_a = (pax2 - pax1) * (pay2 - pay1);
  const float ssum = s_sum;

  for (int t = tid; t < TT; t += 128) {
    const int lab = tlabels[b * TT + t];
    const float cc = -(sl[lab] / ssum);

    const float4 tb = ((const float4*)tboxes)[b * TT + t];
    const float cbox = fabsf(pbv.x - tb.x) + fabsf(pbv.y - tb.y) +
                       fabsf(pbv.z - tb.z) + fabsf(pbv.w - tb.w);

    const float bx1 = tb.x - 0.5f * tb.z, by1 = tb.y - 0.5f * tb.w;
    const float bx2 = tb.x + 0.5f * tb.z, by2 = tb.y + 0.5f * tb.w;
    const float area_b = (bx2 - bx1) * (by2 - by1);

    const float ltx = fmaxf(pax1, bx1), lty = fmaxf(pay1, by1);
    const float rbx = fminf(pax2, bx2), rby = fminf(pay2, by2);
    const float iw = fmaxf(rbx - ltx, 0.0f), ih = fmaxf(rby - lty, 0.0f);
    const float inter = iw * ih;
    const float uni = area_a + area_b - inter;
    const float iou = inter / uni;

    const float cx1 = fminf(pax1, bx1), cy1 = fminf(pay1, by1);
    const float cx2 = fmaxf(pax2, bx2), cy2 = fmaxf(pay2, by2);
    const float cw = fmaxf(cx2 - cx1, 0.0f), ch = fmaxf(cy2 - cy1, 0.0f);
    const float ac = cw * ch;
    const float giou = iou - (ac - uni) / ac;

    const float cval = 5.0f * cbox + cc - 2.0f * giou;
    cost[(size_t)bq * TT + t] = cval;
    if (costT) costT[((size_t)b * TT + t) * QQ + q] = cval;
  }
}

// ---------------- hungarian kernel: ONE WAVE per batch, barrier-free ----
// Column j owned by lane (j&63), slot (j>>6). All Dijkstra state in
// registers: v, minv, way, cost row, used-mask. u lives in 2 regs/lane
// (row lane and row 64+lane) + per-row tree bitmask -> u update is pure
// VALU. Only p[] (and final qpt[]) live in LDS; the hot loop contains a
// single broadcast ds_read (p[j1]). Single wave => lockstep, in-order DS
// per wave => no barriers needed.
__global__ __launch_bounds__(64) void hungarian_kernel(
    const float* __restrict__ cost,    // [B][Q][T]
    const float* __restrict__ costT,   // [B][T][Q] or nullptr
    float* __restrict__ out_q,         // [B][T]
    float* __restrict__ out_t)         // [B][T]
{
  const int b    = blockIdx.x;
  const int lane = threadIdx.x;

  __shared__ int p_lds[QQ + 1];
  __shared__ int qpt[TT];

  // generic addressing: cost value(i0, j) = base[i0*rs + j*cs]
  const float* base;
  size_t rs, cs;
  if (costT) { base = costT + (size_t)b * TT * QQ; rs = QQ; cs = 1; }
  else       { base = cost  + (size_t)b * QQ * TT; rs = 1;  cs = TT; }

  for (int j = lane; j <= QQ; j += 64) p_lds[j] = TT;

  float u0 = 0.0f, u1 = 0.0f;   // u[lane], u[64+lane]
  float v[NK];
#pragma unroll
  for (int k = 0; k < NK; ++k) v[k] = 0.0f;

  // prefetch row 0
  float c[NK];
#pragma unroll
  for (int k = 0; k < NK; ++k) {
    const int j = k * 64 + lane;
    c[k] = (j < QQ) ? base[(size_t)j * cs] : 0.0f;
  }

  for (int i = 0; i < TT; ++i) {
    p_lds[QQ] = i;               // all lanes, same addr, same value

    float minv[NK];
    int   wayr[NK];
#pragma unroll
    for (int k = 0; k < NK; ++k) { minv[k] = INFF; wayr[k] = QQ; }
    unsigned umask = 0;          // used columns (my lane's 15 slots)
    bool t0 = false, t1 = false; // rows in tree: lane, 64+lane

    int i0 = i;
    int j0 = QQ;
    int jfin;

    while (true) {
      // add row i0 to the tree; mark column j0 used (real cols only)
      t0 = t0 || (i0 == lane);
      t1 = t1 || (i0 == 64 + lane);
      if (j0 != QQ) {
        if ((j0 & 63) == lane) umask |= (1u << (j0 >> 6));
      }

      // u[i0] via shfl (i0 uniform)
      const float us  = (i0 < 64) ? u0 : u1;
      const float ui0 = __shfl(us, i0 & 63);

      // scan: update minv/way over unused columns, track local min
      float lmin = INFF;
      int   lidx = QQ;
#pragma unroll
      for (int k = 0; k < NK; ++k) {
        const int j = k * 64 + lane;
        if (j < QQ && !((umask >> k) & 1u)) {
          const float cur = c[k] - ui0 - v[k];
          if (cur < minv[k]) { minv[k] = cur; wayr[k] = j0; }
          if (minv[k] < lmin) { lmin = minv[k]; lidx = j; }
        }
      }

      // wave argmin: pack (monotone(value), index) into u64, min-reduce.
      // lowest-index tie-break matches jnp.argmin.
      unsigned fb = __float_as_uint(lmin);
      fb = (fb & 0x80000000u) ? ~fb : (fb | 0x80000000u);
      unsigned long long key =
          ((unsigned long long)fb << 32) | (unsigned)lidx;
#pragma unroll
      for (int s = 1; s < 64; s <<= 1) {
        const unsigned long long ok = __shfl_xor(key, s);
        key = (ok < key) ? ok : key;
      }
      const int j1 = (int)(key & 0xffffffffu);
      unsigned hb  = (unsigned)(key >> 32);
      const float delta =
          __uint_as_float((hb & 0x80000000u) ? (hb ^ 0x80000000u) : ~hb);

      // row matched to j1 (broadcast LDS read; the only DS op in the loop)
      const int  i0n = p_lds[j1];
      const bool fin = (i0n == TT);

      // prefetch next scan row while the update phase runs
      if (!fin) {
#pragma unroll
        for (int k = 0; k < NK; ++k) {
          const int j = k * 64 + lane;
          if (j < QQ) c[k] = base[(size_t)i0n * rs + (size_t)j * cs];
        }
      }

      // potential updates: all register ops
      u0 += t0 ? delta : 0.0f;
      u1 += t1 ? delta : 0.0f;
#pragma unroll
      for (int k = 0; k < NK; ++k) {
        const bool uk = (umask >> k) & 1u;
        v[k]    -= uk ? delta : 0.0f;
        minv[k] -= uk ? 0.0f  : delta;
      }

      if (fin) { jfin = j1; break; }
      j0 = j1;
      i0 = i0n;
    }

    // augment along the way chain (wave-uniform serial walk)
    int j = jfin;
    while (j != QQ) {
      const int slot = j >> 6;   // uniform
      int wv = wayr[0];
#pragma unroll
      for (int k = 1; k < NK; ++k) if (slot == k) wv = wayr[k];
      const int jn = __shfl(wv, j & 63);
      const int pj = p_lds[jn];  // jn may be QQ -> p_lds[QQ] == i
      p_lds[j] = pj;             // all lanes same addr, same value
      j = jn;
    }

    // prefetch row i+1 (its Dijkstra starts at i0 = i+1)
    if (i + 1 < TT) {
#pragma unroll
      for (int k = 0; k < NK; ++k) {
        const int jj = k * 64 + lane;
        if (jj < QQ) c[k] = base[(size_t)(i + 1) * rs + (size_t)jj * cs];
      }
    }
    asm volatile("" ::: "memory");  // compiler ordering fence (no HW cost)
  }

  // q_per_t: query assigned to each target row
#pragma unroll
  for (int k = 0; k < NK; ++k) {
    const int j = k * 64 + lane;
    if (j < QQ) {
      const int r = p_lds[j];
      if (r < TT) qpt[r] = j;
    }
  }
  __syncthreads();  // once per kernel; cheap insurance before rank pass

  // argsort(q_per_t) via rank counting (values are distinct)
  for (int t = lane; t < TT; t += 64) {
    const int myq = qpt[t];
    int rank = 0;
    for (int t2 = 0; t2 < TT; ++t2) rank += (qpt[t2] < myq) ? 1 : 0;
    out_q[b * TT + rank] = (float)myq;
    out_t[b * TT + rank] = (float)t;
  }
}

extern "C" void kernel_launch(void* const* d_in, const int* in_sizes, int n_in,
                              void* d_out, int out_size, void* d_ws, size_t ws_size,
                              hipStream_t stream) {
  const float* logits  = (const float*)d_in[0];
  const float* pboxes  = (const float*)d_in[1];
  const int*   tlabels = (const int*)d_in[2];
  const float* tboxes  = (const float*)d_in[3];

  float* out  = (float*)d_out;
  float* cost = out;                               // [B][Q][T]
  float* oq   = out + (size_t)BB * QQ * TT;        // [B][T]
  float* ot   = oq + (size_t)BB * TT;              // [B][T]

  const size_t costT_bytes = (size_t)BB * TT * QQ * sizeof(float);
  float* costT = (ws_size >= costT_bytes) ? (float*)d_ws : nullptr;

  hipLaunchKernelGGL(cost_kernel, dim3(BB * QQ), dim3(128), 0, stream,
                     logits, pboxes, tlabels, tboxes, cost, costT);
  hipLaunchKernelGGL(hungarian_kernel, dim3(BB), dim3(64), 0, stream,
                     cost, costT, oq, ot);
}